// Round 5
// baseline (97.267 us; speedup 1.0000x reference)
//
#include <hip/hip_runtime.h>
#include <math.h>

#define N 8
#define C 256
#define L 512
#define K 100
#define NL (N * L)
#define EPSN 1e-8f

// ws layout: znb[NL*C] bf16 | cnb[NL*C] bf16 | partials[2048] f32

__device__ __forceinline__ unsigned short f2bf_rne(float x) {
    unsigned u = __float_as_uint(x);
    u += 0x7fffu + ((u >> 16) & 1u);          // round-to-nearest-even
    return (unsigned short)(u >> 16);
}
__device__ __forceinline__ float bf_lo(unsigned d) { return __uint_as_float(d << 16); }
__device__ __forceinline__ float bf_hi(unsigned d) { return __uint_as_float(d & 0xffff0000u); }

// K1: transpose (N,C,L)->(NL,C), fp32 normalize (clamp 1e-8), cast bf16 RNE.
// Block = 16 l's x 256 c's; 512 blocks (256 z + 256 c, c drops start token).
__global__ __launch_bounds__(256) void prep_kernel(
    const float* __restrict__ z, const float* __restrict__ c,
    unsigned short* __restrict__ znb, unsigned short* __restrict__ cnb)
{
    __shared__ float tile[256 * 17];   // [c][l] +1 pad
    __shared__ float red[256];
    __shared__ float linv[16];

    const int b    = blockIdx.x;
    const int is_c = b >= 256;
    const int bb   = is_c ? b - 256 : b;
    const int n    = bb >> 5;
    const int l0   = (bb & 31) << 4;
    const int ld   = is_c ? (L + 1) : L;
    const float* src = (is_c ? c : z) + (size_t)n * C * ld + (is_c ? 1 : 0) + l0;
    unsigned short* dst = (is_c ? cnb : znb) + (size_t)(n * L + l0) * C;

    const int t = threadIdx.x;
    const int lcl = t & 15;            // local l
    const int cc0 = t >> 4;            // c group

    float ss = 0.f;
    #pragma unroll
    for (int i = 0; i < 16; ++i) {
        const int cidx = i * 16 + cc0;
        const float v = src[(size_t)cidx * ld + lcl];
        tile[cidx * 17 + lcl] = v;
        ss += v * v;
    }
    red[t] = ss;
    __syncthreads();
    if (t < 16) {
        float tot = 0.f;
        #pragma unroll
        for (int j = 0; j < 16; ++j) tot += red[j * 16 + t];
        linv[t] = 1.f / fmaxf(sqrtf(tot), EPSN);
    }
    __syncthreads();
    #pragma unroll
    for (int j = 0; j < 16; ++j)
        dst[(size_t)j * C + t] = f2bf_rne(tile[t * 17 + j] * linv[j]);
}

// K2: 2 waves per row (half the 128 padded targets each), 2 rows per block.
// Per batch of 16: bf16 row gather (512B/wave-op), fp32 dot partials,
// XOR-swizzled ds_write_b32 (conflict-free), ds_read_b128 redistribute,
// 2 shfl to finish. Fixed-shift LSE (logit = 2*cos). No global atomics.
__global__ __launch_bounds__(256, 4) void logits_kernel(
    const unsigned short* __restrict__ znb, const unsigned short* __restrict__ cnb,
    const int* __restrict__ neg,
    const float* __restrict__ z, const float* __restrict__ c,
    float* __restrict__ partials)
{
    __shared__ float buf[4][16 * 64];  // 4 KB per wave
    __shared__ float wacc[4];
    __shared__ float wpos[2];

    const int w    = threadIdx.x >> 6;
    const int lane = threadIdx.x & 63;
    const int rl   = w >> 1;           // row slot in block
    const int h    = w & 1;            // which half of the targets
    const int row  = __builtin_amdgcn_readfirstlane((int)blockIdx.x * 2 + rl);

    // context fragment: cols lane*4 .. lane*4+3 (8B bf16 -> 4 fp32)
    const uint2 cd = *(const uint2*)(cnb + (size_t)row * C + lane * 4);
    const float c0 = bf_lo(cd.x), c1 = bf_hi(cd.x);
    const float c2 = bf_lo(cd.y), c3 = bf_hi(cd.y);

    const int* __restrict__ tbase = neg + (size_t)row * K + h * 64;
    float* __restrict__ bw = &buf[w][0];

    float s_acc = 0.f;
    #pragma unroll 1
    for (int b = 0; b < 4; ++b) {
        // ---- phase 1: 16 gathered bf16 dots -> swizzled LDS partials ----
        #pragma unroll 8
        for (int r = 0; r < 16; ++r) {
            const int j = b * 16 + r;                       // 0..63 in this half
            const bool realn = h ? (j <= K - 64) : (j >= 1);  // is a real negative
            const int off = (j >= 1) ? j - 1 : 0;           // safe in-bounds offset
            int idx = realn ? __builtin_amdgcn_readfirstlane(tbase[off]) : row;
            const uint2 zd = *(const uint2*)(znb + (size_t)idx * C + lane * 4);
            const float p = fmaf(c0, bf_lo(zd.x), fmaf(c1, bf_hi(zd.x),
                             fmaf(c2, bf_lo(zd.y), c3 * bf_hi(zd.y))));
            bw[(r << 6) + (lane ^ (r << 2))] = p;           // 2-way max: free
        }
        // ---- phase 2: redistribute (conflict-free by swizzle), finish ----
        const int nn = lane & 15, q = lane >> 4;
        float4 a = {0.f, 0.f, 0.f, 0.f};
        #pragma unroll
        for (int j2 = 0; j2 < 4; ++j2) {
            const int uu = q * 4 + j2;
            const float4 v = *(const float4*)(bw + (nn << 6) + ((uu ^ nn) << 2));
            a.x += v.x; a.y += v.y; a.z += v.z; a.w += v.w;
        }
        float d = (a.x + a.y) + (a.z + a.w);
        d += __shfl_xor(d, 16, 64);
        d += __shfl_xor(d, 32, 64);
        if (q == 0) {                   // lanes 0..15 own target h*64+b*16+nn
            const int t = h * 64 + b * 16 + nn;
            const float sim2 = d * 2.0f;                    // logit = 2*cos
            if (t == 0) wpos[rl] = sim2;
            bool use = (t <= K);
            if (use && t >= 1 && sim2 > 1.9f) {
                // rare path: exact fp32 equality vs original tensors
                const int idxv = tbase[t - h * 64 - 1];
                const int nr = row >> 9, lr = row & 511;
                const int ni = idxv >> 9, li = idxv & 511;
                bool eq = true;
                for (int e = 0; e < C && eq; ++e)
                    eq = (c[((size_t)nr * C + e) * (L + 1) + lr + 1]
                          == z[((size_t)ni * C + e) * L + li]);
                if (eq) use = false;    // masked -inf -> contributes 0
            }
            if (use) s_acc += __expf(sim2 - 2.0f);
        }
    }
    #pragma unroll
    for (int m = 1; m < 16; m <<= 1) s_acc += __shfl_xor(s_acc, m, 64);
    if (lane == 0) wacc[w] = s_acc;
    __syncthreads();
    if (threadIdx.x == 0) {
        const float t0 = 2.0f + __logf(wacc[0] + wacc[1]) - wpos[0];
        const float t1 = 2.0f + __logf(wacc[2] + wacc[3]) - wpos[1];
        partials[blockIdx.x] = t0 + t1;
    }
}

// K3: reduce 2048 block partials -> mean loss.
__global__ __launch_bounds__(256) void reduce_kernel(
    const float* __restrict__ p, float* __restrict__ out)
{
    __shared__ float red[4];
    const int t = threadIdx.x;
    float s = 0.f;
    #pragma unroll
    for (int k = 0; k < 8; ++k) s += p[t + k * 256];
    #pragma unroll
    for (int m = 1; m < 64; m <<= 1) s += __shfl_xor(s, m, 64);
    if ((t & 63) == 0) red[t >> 6] = s;
    __syncthreads();
    if (t == 0) out[0] = (red[0] + red[1] + red[2] + red[3]) * (1.0f / NL);
}

extern "C" void kernel_launch(void* const* d_in, const int* in_sizes, int n_in,
                              void* d_out, int out_size, void* d_ws, size_t ws_size,
                              hipStream_t stream) {
    const float* z = (const float*)d_in[0];
    const float* c = (const float*)d_in[1];
    const int* neg = (const int*)d_in[2];
    float* out = (float*)d_out;

    unsigned short* znb = (unsigned short*)d_ws;
    unsigned short* cnb = znb + (size_t)NL * C;
    float* partials = (float*)(cnb + (size_t)NL * C);

    prep_kernel<<<512, 256, 0, stream>>>(z, c, znb, cnb);
    logits_kernel<<<NL / 2, 256, 0, stream>>>(znb, cnb, neg, z, c, partials);
    reduce_kernel<<<1, 256, 0, stream>>>(partials, out);
}

// Round 6
// 83.679 us; speedup vs baseline: 1.1624x; 1.1624x over previous
//
#include <hip/hip_runtime.h>
#include <math.h>

#define N 8
#define C 256
#define L 512
#define K 100
#define NL (N * L)
#define EPSN 1e-8f

// ws layout: znb[NL*C] bf16 | cnb[NL*C] bf16 | partials[1024] f32

__device__ __forceinline__ unsigned short f2bf_rne(float x) {
    unsigned u = __float_as_uint(x);
    u += 0x7fffu + ((u >> 16) & 1u);          // round-to-nearest-even
    return (unsigned short)(u >> 16);
}
__device__ __forceinline__ float bf_lo(unsigned d) { return __uint_as_float(d << 16); }
__device__ __forceinline__ float bf_hi(unsigned d) { return __uint_as_float(d & 0xffff0000u); }

// K1: transpose (N,C,L)->(NL,C) + fp32 normalize + bf16 RNE cast.
// 256 blocks: tile = 256 c's x 32 l's -> full 128B-line global reads.
__global__ __launch_bounds__(256) void prep_kernel(
    const float* __restrict__ z, const float* __restrict__ c,
    unsigned short* __restrict__ znb, unsigned short* __restrict__ cnb)
{
    __shared__ float tile[256 * 33];   // [c][l], 33: conflict-free both phases
    __shared__ float red[256];
    __shared__ float linv[32];

    const int b    = blockIdx.x;
    const int is_c = b >= 128;
    const int bb   = b & 127;
    const int n    = bb >> 4;            // 16 l-tiles per n
    const int l0   = (bb & 15) << 5;     // 32 l's per block
    const int ld   = is_c ? (L + 1) : L;
    const float* src = (is_c ? c : z) + (size_t)n * C * ld + (is_c ? 1 : 0) + l0;
    unsigned short* dst = (is_c ? cnb : znb) + (size_t)(n * L + l0) * C;

    const int t   = threadIdx.x;
    const int lcl = t & 31;              // local l (128B coalesced in-line)
    const int cg  = t >> 5;              // c group (8 groups)

    float ss = 0.f;
    #pragma unroll
    for (int i = 0; i < 32; ++i) {
        const int cidx = i * 8 + cg;
        const float v = src[(size_t)cidx * ld + lcl];
        tile[cidx * 33 + lcl] = v;
        ss += v * v;
    }
    red[t] = ss;                         // red[cg*32 + lcl]
    __syncthreads();
    if (t < 32) {
        float tot = 0.f;
        #pragma unroll
        for (int j = 0; j < 8; ++j) tot += red[j * 32 + t];
        linv[t] = 1.f / fmaxf(sqrtf(tot), EPSN);
    }
    __syncthreads();
    #pragma unroll
    for (int j = 0; j < 32; ++j)
        dst[(size_t)j * C + t] = f2bf_rne(tile[t * 33 + j] * linv[j]);
}

// K2: one wave per row; TWO targets per gather wave-op (lanes 0-31 = target 2r,
// lanes 32-63 = target 2r+1; 16B/lane covers 8 bf16 channels). 128 padded
// targets in 4 batches of 32. Double-buffered LDS partials; pad-68 layout
// (phase-1 conflict-free). Fixed-shift LSE (logit = 2*cos <= 2). No atomics.
__global__ __launch_bounds__(256) void logits_kernel(
    const unsigned short* __restrict__ znb, const unsigned short* __restrict__ cnb,
    const int* __restrict__ neg,
    const float* __restrict__ z, const float* __restrict__ c,
    float* __restrict__ partials)
{
    __shared__ float buf[4][2 * 16 * 68];   // 8.7 KB per wave (double-buffered)
    __shared__ float wterm[4];

    const int w    = threadIdx.x >> 6;
    const int lane = threadIdx.x & 63;
    const int row  = __builtin_amdgcn_readfirstlane((int)blockIdx.x * 4 + w);
    const int* __restrict__ negp = neg + (size_t)row * K;
    float* __restrict__ bw = &buf[w][0];

    const int h = lane >> 5;             // which target of the pair
    const int k = lane & 31;             // 16B chunk (8 channels) within row

    const uint4 cd = *(const uint4*)(cnb + (size_t)row * C + k * 8);
    const float c0 = bf_lo(cd.x), c1 = bf_hi(cd.x);
    const float c2 = bf_lo(cd.y), c3 = bf_hi(cd.y);
    const float c4 = bf_lo(cd.z), c5 = bf_hi(cd.z);
    const float c6 = bf_lo(cd.w), c7 = bf_hi(cd.w);

    float s_acc = 0.f, pos = 0.f;

    #pragma unroll 2
    for (int b = 0; b < 4; ++b) {
        float* __restrict__ pb = bw + (b & 1) * (16 * 68);
        // ---- phase 1: 16 wave-ops cover 32 targets ----
        #pragma unroll
        for (int r = 0; r < 16; ++r) {
            const int t0 = b * 32 + 2 * r;
            const int i0 = (t0 == 0) ? row :
                ((t0 <= K) ? __builtin_amdgcn_readfirstlane(negp[t0 - 1]) : row);
            const int i1 = (t0 + 1 <= K) ?
                __builtin_amdgcn_readfirstlane(negp[t0]) : row;
            const int idx = h ? i1 : i0;
            const uint4 zd = *(const uint4*)(znb + (size_t)idx * C + k * 8);
            const float p =
                fmaf(c0, bf_lo(zd.x), fmaf(c1, bf_hi(zd.x),
                fmaf(c2, bf_lo(zd.y), fmaf(c3, bf_hi(zd.y),
                fmaf(c4, bf_lo(zd.z), fmaf(c5, bf_hi(zd.z),
                fmaf(c6, bf_lo(zd.w), c7 * bf_hi(zd.w))))))));
            pb[r * 68 + h * 32 + k] = p;   // banks (4r+k)%32: conflict-free
        }
        // ---- phase 2: lane (tt,hl) sums 16 of target tt's 32 partials ----
        const int tt = lane & 31, hl = lane >> 5;
        const int rr = tt >> 1, hh = tt & 1;
        const float* q = pb + rr * 68 + hh * 32 + hl * 16;
        const float4 a0 = *(const float4*)(q);
        const float4 a1 = *(const float4*)(q + 4);
        const float4 a2 = *(const float4*)(q + 8);
        const float4 a3 = *(const float4*)(q + 12);
        float d = ((a0.x + a0.y) + (a0.z + a0.w))
                + ((a1.x + a1.y) + (a1.z + a1.w))
                + ((a2.x + a2.y) + (a2.z + a2.w))
                + ((a3.x + a3.y) + (a3.z + a3.w));
        d += __shfl_xor(d, 32, 64);          // join the two 16-partial halves

        const int t = b * 32 + tt;
        const float sim2 = d * 2.0f;         // logit = 2*cos, max = 2 exactly
        if (t == 0 && hl == 0) pos = sim2;

        bool use = (hl == 0) && (t <= K);
        if (use && t >= 1 && sim2 > 1.9f) {  // exact-equal mask (rare path)
            const int idxv = negp[t - 1];
            const int nr = row >> 9, lr = row & 511;
            const int ni = idxv >> 9, li = idxv & 511;
            bool eq = true;
            for (int e = 0; e < C && eq; ++e)
                eq = (c[((size_t)nr * C + e) * (L + 1) + lr + 1]
                      == z[((size_t)ni * C + e) * L + li]);
            if (eq) use = false;             // masked -inf -> contributes 0
        }
        if (use) s_acc += __expf(sim2 - 2.0f);
    }

    #pragma unroll
    for (int m = 1; m < 64; m <<= 1) s_acc += __shfl_xor(s_acc, m, 64);
    if (lane == 0) wterm[w] = 2.0f + __logf(s_acc) - pos;
    __syncthreads();
    if (threadIdx.x == 0)
        partials[blockIdx.x] = wterm[0] + wterm[1] + wterm[2] + wterm[3];
}

// K3: reduce 1024 block partials -> mean loss.
__global__ __launch_bounds__(256) void reduce_kernel(
    const float* __restrict__ p, float* __restrict__ out)
{
    __shared__ float red[4];
    const int t = threadIdx.x;
    float s = p[t] + p[t + 256] + p[t + 512] + p[t + 768];
    #pragma unroll
    for (int m = 1; m < 64; m <<= 1) s += __shfl_xor(s, m, 64);
    if ((t & 63) == 0) red[t >> 6] = s;
    __syncthreads();
    if (t == 0) out[0] = (red[0] + red[1] + red[2] + red[3]) * (1.0f / NL);
}

extern "C" void kernel_launch(void* const* d_in, const int* in_sizes, int n_in,
                              void* d_out, int out_size, void* d_ws, size_t ws_size,
                              hipStream_t stream) {
    const float* z = (const float*)d_in[0];
    const float* c = (const float*)d_in[1];
    const int* neg = (const int*)d_in[2];
    float* out = (float*)d_out;

    unsigned short* znb = (unsigned short*)d_ws;
    unsigned short* cnb = znb + (size_t)NL * C;
    float* partials = (float*)(cnb + (size_t)NL * C);

    prep_kernel<<<256, 256, 0, stream>>>(z, c, znb, cnb);
    logits_kernel<<<NL / 4, 256, 0, stream>>>(znb, cnb, neg, z, c, partials);
    reduce_kernel<<<1, 256, 0, stream>>>(partials, out);
}

// Round 7
// 82.338 us; speedup vs baseline: 1.1813x; 1.0163x over previous
//
#include <hip/hip_runtime.h>
#include <math.h>

#define N 8
#define C 256
#define L 512
#define K 100
#define NL (N * L)
#define EPSN 1e-8f

// ws layout: cn[NL*C] f32 (4 MB) | zq[NL*C] fp8-e4m3 (1 MB) | partials[1024] f32

typedef float v2f __attribute__((ext_vector_type(2)));

__device__ __forceinline__ unsigned char f2fp8(float x) {
    return (unsigned char)(__builtin_amdgcn_cvt_pk_fp8_f32(x, x, 0, false) & 0xff);
}

// K1: transpose (N,C,L)->(NL,C) + fp32 normalize; c -> fp32 cn, z -> fp8 zq.
// 256 blocks: tile = 256 c's x 32 l's, full-128B-line global reads.
__global__ __launch_bounds__(256) void prep_kernel(
    const float* __restrict__ z, const float* __restrict__ c,
    unsigned char* __restrict__ zq, float* __restrict__ cn)
{
    __shared__ float tile[256 * 33];   // [c][l], pad 33: conflict-free
    __shared__ float red[256];
    __shared__ float linv[32];

    const int b    = blockIdx.x;
    const int is_c = b >= 128;
    const int bb   = b & 127;
    const int n    = bb >> 4;
    const int l0   = (bb & 15) << 5;     // 32 l's per block
    const int ld   = is_c ? (L + 1) : L;
    const float* src = (is_c ? c : z) + (size_t)n * C * ld + (is_c ? 1 : 0) + l0;

    const int t   = threadIdx.x;
    const int lcl = t & 31;              // local l (128B coalesced)
    const int cg  = t >> 5;              // c group

    float ss = 0.f;
    #pragma unroll
    for (int i = 0; i < 32; ++i) {
        const int cidx = i * 8 + cg;
        const float v = src[(size_t)cidx * ld + lcl];
        tile[cidx * 33 + lcl] = v;
        ss += v * v;
    }
    red[t] = ss;
    __syncthreads();
    if (t < 32) {
        float tot = 0.f;
        #pragma unroll
        for (int j = 0; j < 8; ++j) tot += red[j * 32 + t];
        linv[t] = 1.f / fmaxf(sqrtf(tot), EPSN);
    }
    __syncthreads();
    if (is_c) {
        float* dst = cn + (size_t)(n * L + l0) * C;
        #pragma unroll
        for (int j = 0; j < 32; ++j)
            dst[(size_t)j * C + t] = tile[t * 33 + j] * linv[j];   // coalesced
    } else {
        unsigned char* dst = zq + (size_t)(n * L + l0) * C;
        #pragma unroll
        for (int j = 0; j < 32; ++j)
            dst[(size_t)j * C + t] = f2fp8(tile[t * 33 + j] * linv[j]);
    }
}

// K2: one wave per row; FOUR targets per gather wave-op (fp8 row = 256B,
// 16 lanes/target x 16B = 16 channels/lane). 128 padded targets in 2 batches
// of 64. Phase 2: each lane owns one target, 4 in-lane b128 reads, no shfl.
// Fixed-shift LSE (logit = 2*cos <= 2). No global atomics.
__global__ __launch_bounds__(256, 4) void logits_kernel(
    const unsigned char* __restrict__ zq, const float* __restrict__ cn,
    const int* __restrict__ neg,
    const float* __restrict__ z, const float* __restrict__ c,
    float* __restrict__ partials)
{
    __shared__ float buf[4][2 * 16 * 68];   // 8.7 KB per wave, double-buffered
    __shared__ float wterm[4];

    const int w = threadIdx.x >> 6, lane = threadIdx.x & 63;
    const int row = __builtin_amdgcn_readfirstlane((int)blockIdx.x * 4 + w);
    const int* __restrict__ negp = neg + (size_t)row * K;
    const int g = lane >> 4;             // target within quad
    const int k = lane & 15;             // 16-channel chunk

    const float* crow = cn + (size_t)row * C + k * 16;
    const float4 ca = *(const float4*)(crow);
    const float4 cb = *(const float4*)(crow + 4);
    const float4 cc = *(const float4*)(crow + 8);
    const float4 ce = *(const float4*)(crow + 12);

    float s_acc = 0.f, pos = 0.f;

    #pragma unroll 1
    for (int b = 0; b < 2; ++b) {
        float* __restrict__ pb = &buf[w][b * (16 * 68)];
        // ---- phase 1: 16 wave-ops cover 64 targets ----
        #pragma unroll 8
        for (int r = 0; r < 16; ++r) {
            const int t0 = b * 64 + 4 * r;
            const int i0 = (t0 == 0) ? row
                : ((t0 <= K) ? __builtin_amdgcn_readfirstlane(negp[t0 - 1]) : row);
            const int i1 = (t0 + 1 <= K) ? __builtin_amdgcn_readfirstlane(negp[t0]) : row;
            const int i2 = (t0 + 2 <= K) ? __builtin_amdgcn_readfirstlane(negp[t0 + 1]) : row;
            const int i3 = (t0 + 3 <= K) ? __builtin_amdgcn_readfirstlane(negp[t0 + 2]) : row;
            const int idx = (g == 0) ? i0 : (g == 1) ? i1 : (g == 2) ? i2 : i3;
            const uint4 zd = *(const uint4*)(zq + (size_t)idx * C + k * 16);
            v2f q;
            float d;
            q = __builtin_amdgcn_cvt_pk_f32_fp8(zd.x, false);
            d = ca.x * q.x; d = fmaf(ca.y, q.y, d);
            q = __builtin_amdgcn_cvt_pk_f32_fp8(zd.x, true);
            d = fmaf(ca.z, q.x, d); d = fmaf(ca.w, q.y, d);
            q = __builtin_amdgcn_cvt_pk_f32_fp8(zd.y, false);
            d = fmaf(cb.x, q.x, d); d = fmaf(cb.y, q.y, d);
            q = __builtin_amdgcn_cvt_pk_f32_fp8(zd.y, true);
            d = fmaf(cb.z, q.x, d); d = fmaf(cb.w, q.y, d);
            q = __builtin_amdgcn_cvt_pk_f32_fp8(zd.z, false);
            d = fmaf(cc.x, q.x, d); d = fmaf(cc.y, q.y, d);
            q = __builtin_amdgcn_cvt_pk_f32_fp8(zd.z, true);
            d = fmaf(cc.z, q.x, d); d = fmaf(cc.w, q.y, d);
            q = __builtin_amdgcn_cvt_pk_f32_fp8(zd.w, false);
            d = fmaf(ce.x, q.x, d); d = fmaf(ce.y, q.y, d);
            q = __builtin_amdgcn_cvt_pk_f32_fp8(zd.w, true);
            d = fmaf(ce.z, q.x, d); d = fmaf(ce.w, q.y, d);
            pb[r * 68 + g * 16 + k] = d;     // 2-way bank alias: free
        }
        // ---- phase 2: lane owns target t = b*64 + lane ----
        const int t = b * 64 + lane;
        const float* qp = pb + (lane >> 2) * 68 + (lane & 3) * 16;
        const float4 a0 = *(const float4*)(qp);
        const float4 a1 = *(const float4*)(qp + 4);
        const float4 a2 = *(const float4*)(qp + 8);
        const float4 a3 = *(const float4*)(qp + 12);
        const float dt = ((a0.x + a0.y) + (a0.z + a0.w))
                       + ((a1.x + a1.y) + (a1.z + a1.w))
                       + ((a2.x + a2.y) + (a2.z + a2.w))
                       + ((a3.x + a3.y) + (a3.z + a3.w));
        const float sim2 = dt * 2.0f;        // logit = 2*cos, max = 2
        if (t == 0) pos = sim2;              // lane 0, batch 0

        bool use = (t <= K);
        if (use && t >= 1 && sim2 > 1.9f) {  // exact-equal mask (rare path)
            const int idxv = negp[t - 1];
            const int nr = row >> 9, lr = row & 511;
            const int ni = idxv >> 9, li = idxv & 511;
            bool eq = true;
            for (int e = 0; e < C && eq; ++e)
                eq = (c[((size_t)nr * C + e) * (L + 1) + lr + 1]
                      == z[((size_t)ni * C + e) * L + li]);
            if (eq) use = false;             // masked -inf -> contributes 0
        }
        if (use) s_acc += __expf(sim2 - 2.0f);
    }

    #pragma unroll
    for (int m = 1; m < 64; m <<= 1) s_acc += __shfl_xor(s_acc, m, 64);
    if (lane == 0) wterm[w] = 2.0f + __logf(s_acc) - pos;
    __syncthreads();
    if (threadIdx.x == 0)
        partials[blockIdx.x] = wterm[0] + wterm[1] + wterm[2] + wterm[3];
}

// K3: reduce 1024 block partials -> mean loss.
__global__ __launch_bounds__(256) void reduce_kernel(
    const float* __restrict__ p, float* __restrict__ out)
{
    __shared__ float red[4];
    const int t = threadIdx.x;
    float s = p[t] + p[t + 256] + p[t + 512] + p[t + 768];
    #pragma unroll
    for (int m = 1; m < 64; m <<= 1) s += __shfl_xor(s, m, 64);
    if ((t & 63) == 0) red[t >> 6] = s;
    __syncthreads();
    if (t == 0) out[0] = (red[0] + red[1] + red[2] + red[3]) * (1.0f / NL);
}

extern "C" void kernel_launch(void* const* d_in, const int* in_sizes, int n_in,
                              void* d_out, int out_size, void* d_ws, size_t ws_size,
                              hipStream_t stream) {
    const float* z = (const float*)d_in[0];
    const float* c = (const float*)d_in[1];
    const int* neg = (const int*)d_in[2];
    float* out = (float*)d_out;

    float* cn = (float*)d_ws;
    unsigned char* zq = (unsigned char*)(cn + (size_t)NL * C);
    float* partials = (float*)(zq + (size_t)NL * C);

    prep_kernel<<<256, 256, 0, stream>>>(z, c, zq, cn);
    logits_kernel<<<NL / 4, 256, 0, stream>>>(zq, cn, neg, z, c, partials);
    reduce_kernel<<<1, 256, 0, stream>>>(partials, out);
}